// Round 1
// baseline (813.026 us; speedup 1.0000x reference)
//
#include <hip/hip_runtime.h>
#include <hip/hip_bf16.h>

#define N_IN   256
#define N_OUTC 128
#define SC_EPT 8          // edges per thread in scatter

typedef __attribute__((ext_vector_type(8))) short bf16x8;
typedef __attribute__((ext_vector_type(4))) float f32x4;
typedef unsigned short ushort_t;
typedef unsigned int uint_t;

__device__ inline unsigned short f2bf(float f) {
    unsigned u = __float_as_uint(f);
    unsigned r = u + 0x7fffu + ((u >> 16) & 1u);
    return (unsigned short)(r >> 16);
}
__device__ inline float bf_lo(uint_t g) { return __uint_as_float(g << 16); }
__device__ inline float bf_hi(uint_t g) { return __uint_as_float(g & 0xFFFF0000u); }

// ---------------- W fp32 [128,256] -> bf16 ----------------
__global__ void cvtW_kernel(const float* __restrict__ W, ushort_t* __restrict__ wb, int n) {
    int i = blockIdx.x * blockDim.x + threadIdx.x;
    if (i < n) wb[i] = f2bf(W[i]);
}

// ---------------- fused: row histogram (fire-and-forget atomics) + gemm ----------------
// h = x @ W^T + b, bf16 out.  Histogram prologue: no-return global atomics, hidden
// behind the MFMA work — no wave ever waits on an atomic result in this kernel.
__global__ __launch_bounds__(256) void fused_hist_gemm_kernel(
        const int* __restrict__ rows, int E, int histPerBlock, int* __restrict__ rowCnt,
        const float* __restrict__ x, const ushort_t* __restrict__ wb,
        const float* __restrict__ b, ushort_t* __restrict__ h16) {
    const int tid = threadIdx.x;

    // ---- histogram prologue ----
    {
        int e0 = blockIdx.x * histPerBlock;
        int e1 = e0 + histPerBlock; if (e1 > E) e1 = E;
        for (int e = e0 + tid; e < e1; e += 256)
            atomicAdd(&rowCnt[rows[e]], 1);          // result unused -> no-return atomic
    }

    // ---- gemm: 16 rows x 128 cols per block ----
    const int wave = tid >> 6;
    const int lane = tid & 63;
    const int quad = lane >> 4;
    const int l16  = lane & 15;
    const int m0   = blockIdx.x * 16;
    const int colbase = wave * 32;

    f32x4 acc0 = {0.f, 0.f, 0.f, 0.f};
    f32x4 acc1 = {0.f, 0.f, 0.f, 0.f};

    const float* xrow = x + (size_t)(m0 + l16) * N_IN + quad * 8;   // A: m=lane&15, k=quad*8+j
    const ushort_t* w0 = wb + (size_t)(colbase + l16) * N_IN + quad * 8;
    const ushort_t* w1 = w0 + 16 * N_IN;

    #pragma unroll
    for (int kb = 0; kb < N_IN; kb += 32) {
        float4 a0 = *(const float4*)(xrow + kb);
        float4 a1 = *(const float4*)(xrow + kb + 4);
        union { bf16x8 v; __hip_bfloat162 h2[4]; } u;
        u.h2[0] = __float22bfloat162_rn(make_float2(a0.x, a0.y));
        u.h2[1] = __float22bfloat162_rn(make_float2(a0.z, a0.w));
        u.h2[2] = __float22bfloat162_rn(make_float2(a1.x, a1.y));
        u.h2[3] = __float22bfloat162_rn(make_float2(a1.z, a1.w));
        bf16x8 bf0 = *(const bf16x8*)(w0 + kb);
        bf16x8 bf1 = *(const bf16x8*)(w1 + kb);
        acc0 = __builtin_amdgcn_mfma_f32_16x16x32_bf16(u.v, bf0, acc0, 0, 0, 0);
        acc1 = __builtin_amdgcn_mfma_f32_16x16x32_bf16(u.v, bf1, acc1, 0, 0, 0);
    }

    // C/D: row = quad*4 + reg, col = lane&15
    const int c0 = colbase + l16;
    const int c1 = c0 + 16;
    const float bv0 = b[c0];
    const float bv1 = b[c1];
    ushort_t* hp = h16 + (size_t)(m0 + quad * 4) * N_OUTC;
    #pragma unroll
    for (int r = 0; r < 4; r++) {
        hp[(size_t)r * N_OUTC + c0] = f2bf(acc0[r] + bv0);
        hp[(size_t)r * N_OUTC + c1] = f2bf(acc1[r] + bv1);
    }
}

// ---------------- exclusive scan of rowCnt[Ndst] (1 block, 1024 thr) ----------------
// thread t owns a contiguous chunk of npt rows: serial sum -> block scan -> serial writeback.
__global__ __launch_bounds__(1024) void scan_kernel(const int* __restrict__ rowCnt,
                                                    int* __restrict__ rowStart,
                                                    int* __restrict__ rowFill, int Ndst) {
    __shared__ int a[1024], bsh[1024];
    const int tid = threadIdx.x;
    const int npt = (Ndst + 1023) >> 10;
    const int base = tid * npt;
    int s = 0;
    for (int i = 0; i < npt; i++) {
        int idx = base + i;
        if (idx < Ndst) s += rowCnt[idx];
    }
    a[tid] = s; __syncthreads();
    int* src = a; int* dst = bsh;
    for (int off = 1; off < 1024; off <<= 1) {
        dst[tid] = src[tid] + ((tid >= off) ? src[tid - off] : 0);
        __syncthreads();
        int* t = src; src = dst; dst = t;
    }
    int run = tid ? src[tid - 1] : 0;
    for (int i = 0; i < npt; i++) {
        int idx = base + i;
        if (idx < Ndst) {
            rowStart[idx] = run;
            rowFill[idx]  = run;
            run += rowCnt[idx];
        }
    }
}

// ---------------- scatter: edge -> csr[rowFill[r]++] (direct counting sort) ----------------
__global__ __launch_bounds__(256) void scatter_kernel(const int* __restrict__ rows,
                                                      const int* __restrict__ cols,
                                                      const float* __restrict__ vals, int E,
                                                      int* __restrict__ rowFill,
                                                      int2* __restrict__ csr) {
    const int base = blockIdx.x * (256 * SC_EPT) + threadIdx.x;
    #pragma unroll
    for (int k = 0; k < SC_EPT; k++) {
        int e = base + k * 256;
        if (e < E) {
            int r = rows[e];
            int c = cols[e];
            float v = vals[e];
            int pos = atomicAdd(&rowFill[r], 1);
            csr[pos] = make_int2(c, __float_as_int(v));
        }
    }
}

// ---------------- SpMM: wave per dst row, coalesced edge loads + shfl broadcast ----------------
__global__ __launch_bounds__(256) void spmm_concat_kernel(const ushort_t* __restrict__ h16,
                                                          const int* __restrict__ rowStart,
                                                          const int* __restrict__ rowCnt,
                                                          const int2* __restrict__ csr,
                                                          const int* __restrict__ prev,
                                                          float* __restrict__ out, int Ndst) {
    int r = blockIdx.x * 4 + (threadIdx.x >> 6);
    if (r >= Ndst) return;
    const int lane = threadIdx.x & 63;
    const int cnt = rowCnt[r];
    const int2* bk = csr + rowStart[r];

    float2 acc = {0.f, 0.f};
    for (int bse = 0; bse < cnt; bse += 64) {
        int idx = bse + lane;
        int2 my = make_int2(0, 0);             // pad: v=0 -> zero contribution, c=0 safe
        if (idx < cnt) my = bk[idx];
        int m = cnt - bse; if (m > 64) m = 64;
        int mg = (m + 7) & ~7;
        for (int j = 0; j < mg; j += 8) {
            int c0 = __shfl(my.x, j + 0), c1 = __shfl(my.x, j + 1);
            int c2 = __shfl(my.x, j + 2), c3 = __shfl(my.x, j + 3);
            int c4 = __shfl(my.x, j + 4), c5 = __shfl(my.x, j + 5);
            int c6 = __shfl(my.x, j + 6), c7 = __shfl(my.x, j + 7);
            uint_t g0 = *(const uint_t*)(h16 + (size_t)c0 * N_OUTC + 2 * lane);
            uint_t g1 = *(const uint_t*)(h16 + (size_t)c1 * N_OUTC + 2 * lane);
            uint_t g2 = *(const uint_t*)(h16 + (size_t)c2 * N_OUTC + 2 * lane);
            uint_t g3 = *(const uint_t*)(h16 + (size_t)c3 * N_OUTC + 2 * lane);
            uint_t g4 = *(const uint_t*)(h16 + (size_t)c4 * N_OUTC + 2 * lane);
            uint_t g5 = *(const uint_t*)(h16 + (size_t)c5 * N_OUTC + 2 * lane);
            uint_t g6 = *(const uint_t*)(h16 + (size_t)c6 * N_OUTC + 2 * lane);
            uint_t g7 = *(const uint_t*)(h16 + (size_t)c7 * N_OUTC + 2 * lane);
            float v0 = __int_as_float(__shfl(my.y, j + 0));
            float v1 = __int_as_float(__shfl(my.y, j + 1));
            float v2 = __int_as_float(__shfl(my.y, j + 2));
            float v3 = __int_as_float(__shfl(my.y, j + 3));
            float v4 = __int_as_float(__shfl(my.y, j + 4));
            float v5 = __int_as_float(__shfl(my.y, j + 5));
            float v6 = __int_as_float(__shfl(my.y, j + 6));
            float v7 = __int_as_float(__shfl(my.y, j + 7));
            acc.x += v0 * bf_lo(g0); acc.y += v0 * bf_hi(g0);
            acc.x += v1 * bf_lo(g1); acc.y += v1 * bf_hi(g1);
            acc.x += v2 * bf_lo(g2); acc.y += v2 * bf_hi(g2);
            acc.x += v3 * bf_lo(g3); acc.y += v3 * bf_hi(g3);
            acc.x += v4 * bf_lo(g4); acc.y += v4 * bf_hi(g4);
            acc.x += v5 * bf_lo(g5); acc.y += v5 * bf_hi(g5);
            acc.x += v6 * bf_lo(g6); acc.y += v6 * bf_hi(g6);
            acc.x += v7 * bf_lo(g7); acc.y += v7 * bf_hi(g7);
        }
    }

    int p = prev[r];
    uint_t g = *(const uint_t*)(h16 + (size_t)p * N_OUTC + 2 * lane);
    float2* o = (float2*)(out + (size_t)r * 256);
    o[lane]      = make_float2(bf_lo(g), bf_hi(g));
    o[64 + lane] = make_float2(acc.x, acc.y);
}

// ---------------- fallback path (ws too small; not expected) ----------------
__global__ __launch_bounds__(256) void gemm_only_kernel(const float* __restrict__ x,
                                                        const ushort_t* __restrict__ wb,
                                                        const float* __restrict__ b,
                                                        ushort_t* __restrict__ h16) {
    const int tid  = threadIdx.x;
    const int wave = tid >> 6;
    const int lane = tid & 63;
    const int quad = lane >> 4;
    const int l16  = lane & 15;
    const int m0   = blockIdx.x * 16;
    const int colbase = wave * 32;
    f32x4 acc0 = {0.f, 0.f, 0.f, 0.f};
    f32x4 acc1 = {0.f, 0.f, 0.f, 0.f};
    const float* xrow = x + (size_t)(m0 + l16) * N_IN + quad * 8;
    const ushort_t* w0 = wb + (size_t)(colbase + l16) * N_IN + quad * 8;
    const ushort_t* w1 = w0 + 16 * N_IN;
    #pragma unroll
    for (int kb = 0; kb < N_IN; kb += 32) {
        float4 a0 = *(const float4*)(xrow + kb);
        float4 a1 = *(const float4*)(xrow + kb + 4);
        union { bf16x8 v; __hip_bfloat162 h2[4]; } u;
        u.h2[0] = __float22bfloat162_rn(make_float2(a0.x, a0.y));
        u.h2[1] = __float22bfloat162_rn(make_float2(a0.z, a0.w));
        u.h2[2] = __float22bfloat162_rn(make_float2(a1.x, a1.y));
        u.h2[3] = __float22bfloat162_rn(make_float2(a1.z, a1.w));
        bf16x8 bf0 = *(const bf16x8*)(w0 + kb);
        bf16x8 bf1 = *(const bf16x8*)(w1 + kb);
        acc0 = __builtin_amdgcn_mfma_f32_16x16x32_bf16(u.v, bf0, acc0, 0, 0, 0);
        acc1 = __builtin_amdgcn_mfma_f32_16x16x32_bf16(u.v, bf1, acc1, 0, 0, 0);
    }
    const int c0 = colbase + l16;
    const int c1 = c0 + 16;
    const float bv0 = b[c0];
    const float bv1 = b[c1];
    ushort_t* hp = h16 + (size_t)(m0 + quad * 4) * N_OUTC;
    #pragma unroll
    for (int r = 0; r < 4; r++) {
        hp[(size_t)r * N_OUTC + c0] = f2bf(acc0[r] + bv0);
        hp[(size_t)r * N_OUTC + c1] = f2bf(acc1[r] + bv1);
    }
}

__global__ void concat_only_kernel(const ushort_t* __restrict__ h16, const int* __restrict__ prev,
                                   float* __restrict__ out, int Ndst) {
    int t = blockIdx.x * blockDim.x + threadIdx.x;
    int r = t >> 6, lane = t & 63;
    if (r >= Ndst) return;
    uint_t g = *(const uint_t*)(h16 + (size_t)prev[r] * N_OUTC + 2 * lane);
    ((float2*)out)[(size_t)r * 128 + lane] = make_float2(bf_lo(g), bf_hi(g));
}

__global__ void spmm_atomic_kernel(const ushort_t* __restrict__ h16, const int* __restrict__ rows,
                                   const int* __restrict__ cols, const float* __restrict__ vals,
                                   int E, float* __restrict__ out) {
    long long t = (long long)blockIdx.x * blockDim.x + threadIdx.x;
    int e = (int)(t >> 6), lane = (int)(t & 63);
    if (e >= E) return;
    uint_t g = *(const uint_t*)(h16 + (size_t)cols[e] * N_OUTC + 2 * lane);
    float v = vals[e];
    int r = rows[e];
    atomicAdd(&out[(size_t)r * 256 + 128 + 2 * lane],     v * bf_lo(g));
    atomicAdd(&out[(size_t)r * 256 + 128 + 2 * lane + 1], v * bf_hi(g));
}

extern "C" void kernel_launch(void* const* d_in, const int* in_sizes, int n_in,
                              void* d_out, int out_size, void* d_ws, size_t ws_size,
                              hipStream_t stream) {
    const float* x    = (const float*)d_in[0];
    const float* W    = (const float*)d_in[1];
    const float* b    = (const float*)d_in[2];
    const float* vals = (const float*)d_in[3];
    const int*   rows = (const int*)d_in[4];
    const int*   cols = (const int*)d_in[5];
    const int*   prev = (const int*)d_in[6];
    float* out = (float*)d_out;

    const int Nsrc = in_sizes[0] / N_IN;   // 100000
    const int E    = in_sizes[3];          // 3200000
    const int Ndst = in_sizes[6];          // 50000
    const int gemmBlocks = Nsrc / 16;      // 6250
    const int histPerBlock = (E + gemmBlocks - 1) / gemmBlocks;   // 512
    const int scBlocks = (E + 256 * SC_EPT - 1) / (256 * SC_EPT); // 1563

    char* ws = (char*)d_ws;
    size_t off = 0;
    ushort_t* h16 = (ushort_t*)(ws + off);
    off += (size_t)Nsrc * N_OUTC * sizeof(ushort_t);               // 25.6 MB
    ushort_t* wb = (ushort_t*)(ws + off);
    off += (size_t)N_OUTC * N_IN * sizeof(ushort_t);               // 64 KB
    off = (off + 255) & ~(size_t)255;
    int* rowCnt = (int*)(ws + off);                                 // memset zone
    size_t memsetBytes = (size_t)Ndst * sizeof(int);
    off += memsetBytes;
    off = (off + 255) & ~(size_t)255;
    int* rowStart = (int*)(ws + off);
    off += (size_t)Ndst * sizeof(int);
    int* rowFill = (int*)(ws + off);
    off += (size_t)Ndst * sizeof(int);
    off = (off + 255) & ~(size_t)255;
    int2* csr = (int2*)(ws + off);
    off += (size_t)E * sizeof(int2);                               // 25.6 MB

    cvtW_kernel<<<(N_OUTC * N_IN + 255) / 256, 256, 0, stream>>>(W, wb, N_OUTC * N_IN);

    if (off <= ws_size) {
        hipMemsetAsync(rowCnt, 0, memsetBytes, stream);
        fused_hist_gemm_kernel<<<gemmBlocks, 256, 0, stream>>>(
            rows, E, histPerBlock, rowCnt, x, wb, b, h16);
        scan_kernel<<<1, 1024, 0, stream>>>(rowCnt, rowStart, rowFill, Ndst);
        scatter_kernel<<<scBlocks, 256, 0, stream>>>(rows, cols, vals, E, rowFill, csr);
        spmm_concat_kernel<<<(Ndst + 3) / 4, 256, 0, stream>>>(h16, rowStart, rowCnt, csr,
                                                               prev, out, Ndst);
    } else {
        gemm_only_kernel<<<gemmBlocks, 256, 0, stream>>>(x, wb, b, h16);
        hipMemsetAsync(out, 0, (size_t)out_size * sizeof(float), stream);
        concat_only_kernel<<<((size_t)Ndst * 64 + 255) / 256, 256, 0, stream>>>(h16, prev, out, Ndst);
        spmm_atomic_kernel<<<((size_t)E * 64 + 255) / 256, 256, 0, stream>>>(h16, rows, cols, vals, E, out);
    }
}